// Round 8
// baseline (914.993 us; speedup 1.0000x reference)
//
#include <hip/hip_runtime.h>
#include <stdint.h>

#define N_ 8192
#define D_ 1024
// logit = dot(imn,capn)/T; fp8 operands pre-scaled by 16 -> acc = 256*dot
#define EPILOGUE_SCALE (10.0f / 256.0f)
#define ENC_SCALE 16.0f
#define SCALE_1 0x7F7F7F7Fu  // e8m0 1.0 in every byte (MX scales disabled)

typedef float f32x4 __attribute__((ext_vector_type(4)));
typedef int i32x8 __attribute__((ext_vector_type(8)));

// MX-K128 swizzled fragment layout (both operands), 8 MB each.
// 8 slabs (s = K/128), 512 tiles of 16 rows, per tile-slab block 2048 B
// (512 dwords), dword index:
//   idx = s*262144 + til*512 + h*256 + fl*4 + q     (h in {0,1}, fl in [0,64))
//   holds row = til*16 + (fl&15),
//         k-dword (abs) = s*32 + (fl>>4)*8 + h*4 + q
// GEMM lane l reads dwordx4 at dword (blk + l*4) and (blk + 256 + l*4):
// together = 32 consecutive k-bytes for m = l&15, kg = l>>4 -> matches the
// 16x16 A/B operand layout (m = lane&15, k = (lane>>4)*32 + 0..31).
// Layout validated end-to-end: R6/R7 passed with absmax 0.

// Kernel 1: one 16-row tile per block. Phase 1: norms + diag. Phase 2: convert
// to fp8 via LDS. Phase 3: fully-coalesced uint4 stores in MX fragment order.
// Blocks 0..15 also zero rowsum/colsum (replaces memset dispatch).
__global__ __launch_bounds__(256) void normalize_k(
    const float* __restrict__ im, const float* __restrict__ cap,
    unsigned int* __restrict__ imn, unsigned int* __restrict__ capn,
    float* __restrict__ diag, float* __restrict__ sums /* rowsum|colsum */) {
  __shared__ unsigned int ldsA[16 * 257];
  __shared__ unsigned int ldsB[16 * 257];
  const int til = blockIdx.x;
  const int t = threadIdx.x;
  if (til < 16) ((float4*)sums)[til * 256 + t] = (float4){0.f, 0.f, 0.f, 0.f};

  const int rloc = t >> 4, j = t & 15;
  const int row = til * 16 + rloc;
  const float4* __restrict__ aR = (const float4*)(im + (size_t)row * D_);
  const float4* __restrict__ bR = (const float4*)(cap + (size_t)row * D_);

  float ssa = 0.f, ssb = 0.f, dt = 0.f;
#pragma unroll
  for (int i = 0; i < 16; ++i) {
    const float4 a = aR[j + 16 * i];
    const float4 b = bR[j + 16 * i];
    ssa += a.x * a.x + a.y * a.y + a.z * a.z + a.w * a.w;
    ssb += b.x * b.x + b.y * b.y + b.z * b.z + b.w * b.w;
    dt  += a.x * b.x + a.y * b.y + a.z * b.z + a.w * b.w;
  }
#pragma unroll
  for (int o = 1; o < 16; o <<= 1) {  // reduce across the 16 lanes of this row
    ssa += __shfl_xor(ssa, o, 64);
    ssb += __shfl_xor(ssb, o, 64);
    dt  += __shfl_xor(dt, o, 64);
  }
  const float ra = rsqrtf(ssa), rb = rsqrtf(ssb);
  if (j == 0) diag[row] = dt * ra * rb * 10.0f;
  const float sa = ra * ENC_SCALE, sb = rb * ENC_SCALE;

  // phase 2: re-read (L1/L2 hot), convert, stage in LDS [row][k-dword]
#pragma unroll
  for (int i = 0; i < 16; ++i) {
    const float4 a = aR[j + 16 * i];
    const float4 b = bR[j + 16 * i];
    int pa = __builtin_amdgcn_cvt_pk_fp8_f32(a.x * sa, a.y * sa, 0, false);
    pa = __builtin_amdgcn_cvt_pk_fp8_f32(a.z * sa, a.w * sa, pa, true);
    int pb = __builtin_amdgcn_cvt_pk_fp8_f32(b.x * sb, b.y * sb, 0, false);
    pb = __builtin_amdgcn_cvt_pk_fp8_f32(b.z * sb, b.w * sb, pb, true);
    ldsA[rloc * 257 + j + 16 * i] = (unsigned int)pa;
    ldsB[rloc * 257 + j + 16 * i] = (unsigned int)pb;
  }
  __syncthreads();

  // phase 3: coalesced MX-fragment-order stores, 4 uint4 chunks per thread
#pragma unroll
  for (int i = 0; i < 4; ++i) {
    const int cid = i * 256 + t;          // 1024 chunks
    const int s = cid >> 7, rem = cid & 127;
    const int h = rem >> 6, fl = rem & 63;
    const int m15 = fl & 15, kg = fl >> 4;
    const int p0 = s * 32 + kg * 8 + h * 4;   // k-dword base for this chunk
    uint4 va, vb;
    va.x = ldsA[m15 * 257 + p0 + 0]; va.y = ldsA[m15 * 257 + p0 + 1];
    va.z = ldsA[m15 * 257 + p0 + 2]; va.w = ldsA[m15 * 257 + p0 + 3];
    vb.x = ldsB[m15 * 257 + p0 + 0]; vb.y = ldsB[m15 * 257 + p0 + 1];
    vb.z = ldsB[m15 * 257 + p0 + 2]; vb.w = ldsB[m15 * 257 + p0 + 3];
    const size_t d = (size_t)s * 262144 + (size_t)til * 512 + rem * 4;
    *(uint4*)(imn + d) = va;
    *(uint4*)(capn + d) = vb;
  }
}

// helper: load one K=128 operand fragment (two contiguous-1kB dwordx4 pulls).
// CRITICAL: no address-taken locals — vector-element inserts only. R6/R7's
// ((uint4*)&r)[0] = ... pattern created an alloca -> scratch -> 2 GB HBM spill.
__device__ __forceinline__ i32x8 ld_frag(const unsigned char* base, unsigned off) {
  const uint4 lo = *(const uint4*)(base + off);
  const uint4 hi = *(const uint4*)(base + off + 1024);
  i32x8 r;
  r[0] = (int)lo.x; r[1] = (int)lo.y; r[2] = (int)lo.z; r[3] = (int)lo.w;
  r[4] = (int)hi.x; r[5] = (int)hi.y; r[6] = (int)hi.z; r[7] = (int)hi.w;
  return r;
}

// Kernel 2: no-LDS, no-barrier MX-fp8 GEMM (K=128 per MFMA, scales = 1.0)
// + exp + row/col partial sums. 128x128 block tile, 4 waves each a 64x64
// quadrant of 4x4 16x16x128 MFMA tiles. 8 K-slabs, SINGLE-buffered fragments
// (64 staging VGPRs; 3 waves/SIMD provide the latency hiding via the MFMA
// pipe round-robin — m114 co-scheduling).
__global__ __launch_bounds__(256, 3) void gemm_lse_k(
    const unsigned char* __restrict__ A,   // swizzled imn
    const unsigned char* __restrict__ B,   // swizzled capn
    float* __restrict__ rowsum, float* __restrict__ colsum) {
  const int t = threadIdx.x;
  const int w = t >> 6, l = t & 63;
  const int rowBase = blockIdx.x * 128;
  const int colBase = blockIdx.y * 128;
  const int wq_m = (w >> 1) * 64, wq_n = (w & 1) * 64;

  unsigned offA[4], offB[4];
#pragma unroll
  for (int i = 0; i < 4; ++i) {
    offA[i] = (unsigned)((blockIdx.x * 8 + (w >> 1) * 4 + i) * 2048 + l * 16);
    offB[i] = (unsigned)((blockIdx.y * 8 + (w & 1) * 4 + i) * 2048 + l * 16);
  }

  f32x4 acc[4][4];
#pragma unroll
  for (int i = 0; i < 4; ++i)
#pragma unroll
    for (int j = 0; j < 4; ++j)
      acc[i][j] = (f32x4){0.f, 0.f, 0.f, 0.f};

#pragma unroll
  for (int s = 0; s < 8; ++s) {
    const unsigned char* pA = A + (size_t)s * 1048576;
    const unsigned char* pB = B + (size_t)s * 1048576;
    i32x8 af[4], bf[4];
#pragma unroll
    for (int i = 0; i < 4; ++i) {
      af[i] = ld_frag(pA, offA[i]);
      bf[i] = ld_frag(pB, offB[i]);
    }
#pragma unroll
    for (int mt = 0; mt < 4; ++mt)
#pragma unroll
      for (int nt = 0; nt < 4; ++nt)
        acc[mt][nt] = __builtin_amdgcn_mfma_scale_f32_16x16x128_f8f6f4(
            af[mt], bf[nt], acc[mt][nt], 0, 0, 0, SCALE_1, 0, SCALE_1);
  }

  // epilogue: exp (fixed-max LSE; |logit| <= 10, no overflow possible)
#pragma unroll
  for (int mt = 0; mt < 4; ++mt)
#pragma unroll
    for (int nt = 0; nt < 4; ++nt)
#pragma unroll
      for (int r = 0; r < 4; ++r)
        acc[mt][nt][r] = __expf(acc[mt][nt][r] * EPILOGUE_SCALE);

  // C/D layout: col = lane&15, row = (lane>>4)*4 + reg  [measured m89/m91;
  // shape-determined, dtype/format-independent — m121..m128]
#pragma unroll
  for (int mt = 0; mt < 4; ++mt)
#pragma unroll
    for (int r = 0; r < 4; ++r) {
      float v = acc[mt][0][r] + acc[mt][1][r] + acc[mt][2][r] + acc[mt][3][r];
      v += __shfl_xor(v, 1, 64);
      v += __shfl_xor(v, 2, 64);
      v += __shfl_xor(v, 4, 64);
      v += __shfl_xor(v, 8, 64);
      if ((l & 15) == 0)
        atomicAdd(&rowsum[rowBase + wq_m + mt * 16 + (l >> 4) * 4 + r], v);
    }
#pragma unroll
  for (int nt = 0; nt < 4; ++nt) {
    float v = 0.f;
#pragma unroll
    for (int mt = 0; mt < 4; ++mt)
      v += acc[mt][nt][0] + acc[mt][nt][1] + acc[mt][nt][2] + acc[mt][nt][3];
    v += __shfl_xor(v, 16, 64);
    v += __shfl_xor(v, 32, 64);
    if (l < 16)
      atomicAdd(&colsum[colBase + wq_n + nt * 16 + l], v);
  }
}

// Kernel 3: scalar reduce.
__global__ __launch_bounds__(256) void finalize_k(
    const float* __restrict__ rowsum, const float* __restrict__ colsum,
    const float* __restrict__ diag, float* __restrict__ out) {
  const int t = threadIdx.x;
  float lse = 0.f, dg = 0.f;
  for (int i = t; i < N_; i += 256) {
    lse += __logf(rowsum[i]) + __logf(colsum[i]);
    dg += diag[i];
  }
#pragma unroll
  for (int o = 32; o > 0; o >>= 1) {
    lse += __shfl_down(lse, o, 64);
    dg  += __shfl_down(dg, o, 64);
  }
  __shared__ float red[2][4];
  const int w = t >> 6, l = t & 63;
  if (l == 0) { red[0][w] = lse; red[1][w] = dg; }
  __syncthreads();
  if (t == 0) {
    lse = red[0][0] + red[0][1] + red[0][2] + red[0][3];
    dg  = red[1][0] + red[1][1] + red[1][2] + red[1][3];
    out[0] = 0.5f * lse / (float)N_ - dg / (float)N_;
  }
}

extern "C" void kernel_launch(void* const* d_in, const int* in_sizes, int n_in,
                              void* d_out, int out_size, void* d_ws, size_t ws_size,
                              hipStream_t stream) {
  const float* im = (const float*)d_in[0];
  const float* cap = (const float*)d_in[1];
  float* out = (float*)d_out;
  char* ws = (char*)d_ws;
  unsigned char* imn = (unsigned char*)ws;                 // 8 MB fp8 (MX swizzled)
  unsigned char* capn = imn + (size_t)N_ * D_;             // 8 MB fp8 (MX swizzled)
  float* rowsum = (float*)(ws + 2 * (size_t)N_ * D_);
  float* colsum = rowsum + N_;
  float* diag = colsum + N_;

  normalize_k<<<512, 256, 0, stream>>>(im, cap, (unsigned int*)imn,
                                       (unsigned int*)capn, diag, rowsum);
  gemm_lse_k<<<dim3(64, 64), 256, 0, stream>>>(imn, capn, rowsum, colsum);
  finalize_k<<<1, 256, 0, stream>>>(rowsum, colsum, diag, out);
}

// Round 9
// 899.369 us; speedup vs baseline: 1.0174x; 1.0174x over previous
//
#include <hip/hip_runtime.h>
#include <stdint.h>

#define N_ 8192
#define D_ 1024
// logit = dot(imn,capn)/T; fp8 operands pre-scaled by 16 -> acc = 256*dot
#define EPILOGUE_SCALE (10.0f / 256.0f)
#define ENC_SCALE 16.0f
#define SCALE_1 0x7F7F7F7Fu  // e8m0 1.0 in every byte (MX scales disabled)

typedef float f32x4 __attribute__((ext_vector_type(4)));
typedef int i32x4 __attribute__((ext_vector_type(4)));
typedef int i32x8 __attribute__((ext_vector_type(8)));

// MX-K128 swizzled fragment layout (both operands), 8 MB each.
// 8 slabs (s = K/128), 512 tiles of 16 rows, per tile-slab block 2048 B
// (512 dwords), dword index:
//   idx = s*262144 + til*512 + h*256 + fl*4 + q     (h in {0,1}, fl in [0,64))
//   holds row = til*16 + (fl&15),
//         k-dword (abs) = s*32 + (fl>>4)*8 + h*4 + q
// Lane l reads dwordx4 at byte (blk + l*16) and (blk + 1024 + l*16):
// together = 32 consecutive k-bytes for m = l&15, kg = l>>4 -> 16x16x128
// A/B operand layout. Validated end-to-end (R6-R8 absmax 0).

// Kernel 1: one 16-row tile per block. Phase 1: norms + diag. Phase 2: convert
// to fp8 via LDS. Phase 3: fully-coalesced stores in MX fragment order.
// Blocks 0..15 also zero rowsum/colsum (replaces memset dispatch).
__global__ __launch_bounds__(256) void normalize_k(
    const float* __restrict__ im, const float* __restrict__ cap,
    unsigned int* __restrict__ imn, unsigned int* __restrict__ capn,
    float* __restrict__ diag, float* __restrict__ sums /* rowsum|colsum */) {
  __shared__ unsigned int ldsA[16 * 257];
  __shared__ unsigned int ldsB[16 * 257];
  const int til = blockIdx.x;
  const int t = threadIdx.x;
  if (til < 16) ((float4*)sums)[til * 256 + t] = (float4){0.f, 0.f, 0.f, 0.f};

  const int rloc = t >> 4, j = t & 15;
  const int row = til * 16 + rloc;
  const float4* __restrict__ aR = (const float4*)(im + (size_t)row * D_);
  const float4* __restrict__ bR = (const float4*)(cap + (size_t)row * D_);

  float ssa = 0.f, ssb = 0.f, dt = 0.f;
#pragma unroll
  for (int i = 0; i < 16; ++i) {
    const float4 a = aR[j + 16 * i];
    const float4 b = bR[j + 16 * i];
    ssa += a.x * a.x + a.y * a.y + a.z * a.z + a.w * a.w;
    ssb += b.x * b.x + b.y * b.y + b.z * b.z + b.w * b.w;
    dt  += a.x * b.x + a.y * b.y + a.z * b.z + a.w * b.w;
  }
#pragma unroll
  for (int o = 1; o < 16; o <<= 1) {  // reduce across the 16 lanes of this row
    ssa += __shfl_xor(ssa, o, 64);
    ssb += __shfl_xor(ssb, o, 64);
    dt  += __shfl_xor(dt, o, 64);
  }
  const float ra = rsqrtf(ssa), rb = rsqrtf(ssb);
  if (j == 0) diag[row] = dt * ra * rb * 10.0f;
  const float sa = ra * ENC_SCALE, sb = rb * ENC_SCALE;

  // phase 2: re-read (L1/L2 hot), convert, stage in LDS [row][k-dword]
#pragma unroll
  for (int i = 0; i < 16; ++i) {
    const float4 a = aR[j + 16 * i];
    const float4 b = bR[j + 16 * i];
    int pa = __builtin_amdgcn_cvt_pk_fp8_f32(a.x * sa, a.y * sa, 0, false);
    pa = __builtin_amdgcn_cvt_pk_fp8_f32(a.z * sa, a.w * sa, pa, true);
    int pb = __builtin_amdgcn_cvt_pk_fp8_f32(b.x * sb, b.y * sb, 0, false);
    pb = __builtin_amdgcn_cvt_pk_fp8_f32(b.z * sb, b.w * sb, pb, true);
    ldsA[rloc * 257 + j + 16 * i] = (unsigned int)pa;
    ldsB[rloc * 257 + j + 16 * i] = (unsigned int)pb;
  }
  __syncthreads();

  // phase 3: coalesced MX-fragment-order stores (ext-vector types only)
#pragma unroll
  for (int i = 0; i < 4; ++i) {
    const int cid = i * 256 + t;          // 1024 chunks
    const int s = cid >> 7, rem = cid & 127;
    const int h = rem >> 6, fl = rem & 63;
    const int m15 = fl & 15, kg = fl >> 4;
    const int p0 = s * 32 + kg * 8 + h * 4;   // k-dword base for this chunk
    i32x4 va, vb;
    va[0] = (int)ldsA[m15 * 257 + p0 + 0]; va[1] = (int)ldsA[m15 * 257 + p0 + 1];
    va[2] = (int)ldsA[m15 * 257 + p0 + 2]; va[3] = (int)ldsA[m15 * 257 + p0 + 3];
    vb[0] = (int)ldsB[m15 * 257 + p0 + 0]; vb[1] = (int)ldsB[m15 * 257 + p0 + 1];
    vb[2] = (int)ldsB[m15 * 257 + p0 + 2]; vb[3] = (int)ldsB[m15 * 257 + p0 + 3];
    const size_t d = (size_t)s * 262144 + (size_t)til * 512 + rem * 4;
    *(i32x4*)(imn + d) = va;
    *(i32x4*)(capn + d) = vb;
  }
}

// Fragment load: pure SSA — ext-vector loads + shufflevector merge. NO HIP
// struct vectors (uint4 member access), NO address-taken locals, NO arrays.
// (R6: indexed stg[][] -> scratch. R7: ((uint4*)&r)[0] -> scratch. R8:
// (int)lo.x from HIP uint4 -> scratch. All three spilled ~1-2 GB to HBM.)
#define LD_FRAG(dst, p, off)                                                \
  {                                                                         \
    i32x4 lo_ = *(const i32x4*)((p) + (off));                               \
    i32x4 hi_ = *(const i32x4*)((p) + (off) + 1024);                        \
    dst = __builtin_shufflevector(lo_, hi_, 0, 1, 2, 3, 4, 5, 6, 7);        \
  }

#define MFMA_ROW(mt, fa)                                                    \
  acc[mt][0] = __builtin_amdgcn_mfma_scale_f32_16x16x128_f8f6f4(            \
      fa, fb0, acc[mt][0], 0, 0, 0, SCALE_1, 0, SCALE_1);                   \
  acc[mt][1] = __builtin_amdgcn_mfma_scale_f32_16x16x128_f8f6f4(            \
      fa, fb1, acc[mt][1], 0, 0, 0, SCALE_1, 0, SCALE_1);                   \
  acc[mt][2] = __builtin_amdgcn_mfma_scale_f32_16x16x128_f8f6f4(            \
      fa, fb2, acc[mt][2], 0, 0, 0, SCALE_1, 0, SCALE_1);                   \
  acc[mt][3] = __builtin_amdgcn_mfma_scale_f32_16x16x128_f8f6f4(            \
      fa, fb3, acc[mt][3], 0, 0, 0, SCALE_1, 0, SCALE_1);

// Kernel 2: no-LDS, no-barrier MX-fp8 GEMM (K=128 per MFMA, scales = 1.0)
// + exp + row/col partial sums. 128x128 block tile, 4 waves each a 64x64
// quadrant of 4x4 16x16x128 MFMA tiles. 8 K-slabs, single-buffered named
// fragments; 3 waves/SIMD hide latency via MFMA-pipe round-robin (m114).
__global__ __launch_bounds__(256, 3) void gemm_lse_k(
    const unsigned char* __restrict__ A,   // swizzled imn
    const unsigned char* __restrict__ B,   // swizzled capn
    float* __restrict__ rowsum, float* __restrict__ colsum) {
  const int t = threadIdx.x;
  const int w = t >> 6, l = t & 63;
  const int rowBase = blockIdx.x * 128;
  const int colBase = blockIdx.y * 128;
  const int wq_m = (w >> 1) * 64, wq_n = (w & 1) * 64;

  const unsigned offA0 = (unsigned)((blockIdx.x * 8 + (w >> 1) * 4 + 0) * 2048 + l * 16);
  const unsigned offA1 = offA0 + 2048, offA2 = offA0 + 4096, offA3 = offA0 + 6144;
  const unsigned offB0 = (unsigned)((blockIdx.y * 8 + (w & 1) * 4 + 0) * 2048 + l * 16);
  const unsigned offB1 = offB0 + 2048, offB2 = offB0 + 4096, offB3 = offB0 + 6144;

  f32x4 acc[4][4];
#pragma unroll
  for (int i = 0; i < 4; ++i)
#pragma unroll
    for (int j = 0; j < 4; ++j)
      acc[i][j] = (f32x4){0.f, 0.f, 0.f, 0.f};

#pragma unroll
  for (int s = 0; s < 8; ++s) {
    const unsigned char* pA = A + (size_t)s * 1048576;
    const unsigned char* pB = B + (size_t)s * 1048576;
    i32x8 fa0, fa1, fa2, fa3, fb0, fb1, fb2, fb3;
    LD_FRAG(fa0, pA, offA0) LD_FRAG(fa1, pA, offA1)
    LD_FRAG(fa2, pA, offA2) LD_FRAG(fa3, pA, offA3)
    LD_FRAG(fb0, pB, offB0) LD_FRAG(fb1, pB, offB1)
    LD_FRAG(fb2, pB, offB2) LD_FRAG(fb3, pB, offB3)
    MFMA_ROW(0, fa0)
    MFMA_ROW(1, fa1)
    MFMA_ROW(2, fa2)
    MFMA_ROW(3, fa3)
  }

  // epilogue: exp (fixed-max LSE; |logit| <= 10, no overflow possible)
#pragma unroll
  for (int mt = 0; mt < 4; ++mt)
#pragma unroll
    for (int nt = 0; nt < 4; ++nt)
#pragma unroll
      for (int r = 0; r < 4; ++r)
        acc[mt][nt][r] = __expf(acc[mt][nt][r] * EPILOGUE_SCALE);

  // C/D layout: col = lane&15, row = (lane>>4)*4 + reg  [measured m89/m91;
  // shape-determined, dtype/format-independent — m121..m128]
#pragma unroll
  for (int mt = 0; mt < 4; ++mt)
#pragma unroll
    for (int r = 0; r < 4; ++r) {
      float v = acc[mt][0][r] + acc[mt][1][r] + acc[mt][2][r] + acc[mt][3][r];
      v += __shfl_xor(v, 1, 64);
      v += __shfl_xor(v, 2, 64);
      v += __shfl_xor(v, 4, 64);
      v += __shfl_xor(v, 8, 64);
      if ((l & 15) == 0)
        atomicAdd(&rowsum[rowBase + wq_m + mt * 16 + (l >> 4) * 4 + r], v);
    }
#pragma unroll
  for (int nt = 0; nt < 4; ++nt) {
    float v = 0.f;
#pragma unroll
    for (int mt = 0; mt < 4; ++mt)
      v += acc[mt][nt][0] + acc[mt][nt][1] + acc[mt][nt][2] + acc[mt][nt][3];
    v += __shfl_xor(v, 16, 64);
    v += __shfl_xor(v, 32, 64);
    if (l < 16)
      atomicAdd(&colsum[colBase + wq_n + nt * 16 + l], v);
  }
}

// Kernel 3: scalar reduce.
__global__ __launch_bounds__(256) void finalize_k(
    const float* __restrict__ rowsum, const float* __restrict__ colsum,
    const float* __restrict__ diag, float* __restrict__ out) {
  const int t = threadIdx.x;
  float lse = 0.f, dg = 0.f;
  for (int i = t; i < N_; i += 256) {
    lse += __logf(rowsum[i]) + __logf(colsum[i]);
    dg += diag[i];
  }
#pragma unroll
  for (int o = 32; o > 0; o >>= 1) {
    lse += __shfl_down(lse, o, 64);
    dg  += __shfl_down(dg, o, 64);
  }
  __shared__ float red[2][4];
  const int w = t >> 6, l = t & 63;
  if (l == 0) { red[0][w] = lse; red[1][w] = dg; }
  __syncthreads();
  if (t == 0) {
    lse = red[0][0] + red[0][1] + red[0][2] + red[0][3];
    dg  = red[1][0] + red[1][1] + red[1][2] + red[1][3];
    out[0] = 0.5f * lse / (float)N_ - dg / (float)N_;
  }
}

extern "C" void kernel_launch(void* const* d_in, const int* in_sizes, int n_in,
                              void* d_out, int out_size, void* d_ws, size_t ws_size,
                              hipStream_t stream) {
  const float* im = (const float*)d_in[0];
  const float* cap = (const float*)d_in[1];
  float* out = (float*)d_out;
  char* ws = (char*)d_ws;
  unsigned char* imn = (unsigned char*)ws;                 // 8 MB fp8 (MX swizzled)
  unsigned char* capn = imn + (size_t)N_ * D_;             // 8 MB fp8 (MX swizzled)
  float* rowsum = (float*)(ws + 2 * (size_t)N_ * D_);
  float* colsum = rowsum + N_;
  float* diag = colsum + N_;

  normalize_k<<<512, 256, 0, stream>>>(im, cap, (unsigned int*)imn,
                                       (unsigned int*)capn, diag, rowsum);
  gemm_lse_k<<<dim3(64, 64), 256, 0, stream>>>(imn, capn, rowsum, colsum);
  finalize_k<<<1, 256, 0, stream>>>(rowsum, colsum, diag, out);
}

// Round 10
// 268.058 us; speedup vs baseline: 3.4134x; 3.3551x over previous
//
#include <hip/hip_runtime.h>
#include <stdint.h>

#define N_ 8192
#define D_ 1024
// logit = dot(imn,capn)/T; fp8 operands pre-scaled by 16 -> acc = 256*dot
#define EPILOGUE_SCALE (10.0f / 256.0f)
#define ENC_SCALE 16.0f

typedef float f32x4 __attribute__((ext_vector_type(4)));

// K=32 swizzled fragment layout (both operands), 8 MB each [R3/R5-proven]:
//   dword index = s*65536 + tile*128 + fl*2 + h   (s in [0,32), tile in [0,512),
//   fl in [0,64), h in [0,2))
//   holds row = tile*16 + (fl&15), k-dwords [s*8 + (fl>>4)*2 + h]
// A wave's fragment load for (tile, s) is 64 lanes x 8B = 512B contiguous.

// Kernel 1: one 16-row tile per block. Phase 1: norms + diag. Phase 2: convert
// to fp8 via LDS. Phase 3: fully-coalesced uint4 stores in fragment order.
// Blocks 0..15 also zero rowsum/colsum (replaces memset dispatch). [R5 verbatim]
__global__ __launch_bounds__(256) void normalize_k(
    const float* __restrict__ im, const float* __restrict__ cap,
    unsigned int* __restrict__ imn, unsigned int* __restrict__ capn,
    float* __restrict__ diag, float* __restrict__ sums /* rowsum|colsum */) {
  __shared__ unsigned int ldsA[16 * 257];
  __shared__ unsigned int ldsB[16 * 257];
  const int til = blockIdx.x;
  const int t = threadIdx.x;
  if (til < 16) ((float4*)sums)[til * 256 + t] = (float4){0.f, 0.f, 0.f, 0.f};

  const int rloc = t >> 4, j = t & 15;
  const int row = til * 16 + rloc;
  const float4* __restrict__ aR = (const float4*)(im + (size_t)row * D_);
  const float4* __restrict__ bR = (const float4*)(cap + (size_t)row * D_);

  float ssa = 0.f, ssb = 0.f, dt = 0.f;
#pragma unroll
  for (int i = 0; i < 16; ++i) {
    const float4 a = aR[j + 16 * i];
    const float4 b = bR[j + 16 * i];
    ssa += a.x * a.x + a.y * a.y + a.z * a.z + a.w * a.w;
    ssb += b.x * b.x + b.y * b.y + b.z * b.z + b.w * b.w;
    dt  += a.x * b.x + a.y * b.y + a.z * b.z + a.w * b.w;
  }
#pragma unroll
  for (int o = 1; o < 16; o <<= 1) {  // reduce across the 16 lanes of this row
    ssa += __shfl_xor(ssa, o, 64);
    ssb += __shfl_xor(ssb, o, 64);
    dt  += __shfl_xor(dt, o, 64);
  }
  const float ra = rsqrtf(ssa), rb = rsqrtf(ssb);
  if (j == 0) diag[row] = dt * ra * rb * 10.0f;
  const float sa = ra * ENC_SCALE, sb = rb * ENC_SCALE;

  // phase 2: re-read (L1/L2 hot), convert, stage in LDS [row][k-dword]
#pragma unroll
  for (int i = 0; i < 16; ++i) {
    const float4 a = aR[j + 16 * i];
    const float4 b = bR[j + 16 * i];
    int pa = __builtin_amdgcn_cvt_pk_fp8_f32(a.x * sa, a.y * sa, 0, false);
    pa = __builtin_amdgcn_cvt_pk_fp8_f32(a.z * sa, a.w * sa, pa, true);
    int pb = __builtin_amdgcn_cvt_pk_fp8_f32(b.x * sb, b.y * sb, 0, false);
    pb = __builtin_amdgcn_cvt_pk_fp8_f32(b.z * sb, b.w * sb, pb, true);
    ldsA[rloc * 257 + j + 16 * i] = (unsigned int)pa;
    ldsB[rloc * 257 + j + 16 * i] = (unsigned int)pb;
  }
  __syncthreads();

  // phase 3: coalesced fragment-order stores, 4 uint4 chunks per thread
#pragma unroll
  for (int i = 0; i < 4; ++i) {
    const int cid = i * 256 + t;       // 1024 chunks: slab s, 16B chunk c4
    const int s = cid >> 5, c4 = cid & 31;
    uint4 va, vb;
#pragma unroll
    for (int q = 0; q < 4; ++q) {
      const int u = c4 * 4 + q;        // dword within this tile's 128-dword run
      const int fl = u >> 1, h = u & 1;
      const int m15 = fl & 15, kgl = fl >> 4;
      const int p = s * 8 + kgl * 2 + h;
      ((unsigned int*)&va)[q] = ldsA[m15 * 257 + p];
      ((unsigned int*)&vb)[q] = ldsB[m15 * 257 + p];
    }
    const size_t d = (size_t)s * 65536 + (size_t)til * 128 + c4 * 4;
    *(uint4*)(imn + d) = va;
    *(uint4*)(capn + d) = vb;
  }
}

// Kernel 2: no-LDS, no-barrier fp8 GEMM + exp + row/col partial sums.
// 256x128 block tile, 4 waves each a 64x128 slice (4x8 grid of 16x16x32
// MFMA tiles) -> unique L2/L3 fragment traffic drops 1.07 GB -> 786 MB and
// MFMA-per-load doubles vs R5's 128x128. Non-scaled fp8 MFMA with `long`
// operands (R3/R5-proven clean codegen; mfma_scale spilled to scratch in
// R6-R9 under three different staging styles — abandoned).
__global__ __launch_bounds__(256, 2) void gemm_lse_k(
    const unsigned char* __restrict__ A,   // swizzled imn
    const unsigned char* __restrict__ B,   // swizzled capn
    float* __restrict__ rowsum, float* __restrict__ colsum) {
  const int t = threadIdx.x;
  const int w = t >> 6, l = t & 63;
  const int rowBase = blockIdx.x * 256;
  const int colBase = blockIdx.y * 128;

  unsigned offA[4], offB[8];
#pragma unroll
  for (int i = 0; i < 4; ++i)
    offA[i] = (unsigned)((blockIdx.x * 16 + w * 4 + i) * 512 + l * 8);
#pragma unroll
  for (int j = 0; j < 8; ++j)
    offB[j] = (unsigned)((blockIdx.y * 8 + j) * 512 + l * 8);

  f32x4 acc[4][8];
#pragma unroll
  for (int i = 0; i < 4; ++i)
#pragma unroll
    for (int j = 0; j < 8; ++j)
      acc[i][j] = (f32x4){0.f, 0.f, 0.f, 0.f};

  long a0[4], b0[8], a1[4], b1[8];
#pragma unroll
  for (int i = 0; i < 4; ++i) a0[i] = *(const long*)(A + offA[i]);
#pragma unroll
  for (int j = 0; j < 8; ++j) b0[j] = *(const long*)(B + offB[j]);

#pragma unroll
  for (int s = 0; s < 32; s += 2) {
    {  // prefetch slab s+1
      const unsigned char* pA = A + (size_t)(s + 1) * 262144;
      const unsigned char* pB = B + (size_t)(s + 1) * 262144;
#pragma unroll
      for (int i = 0; i < 4; ++i) a1[i] = *(const long*)(pA + offA[i]);
#pragma unroll
      for (int j = 0; j < 8; ++j) b1[j] = *(const long*)(pB + offB[j]);
    }
#pragma unroll
    for (int mt = 0; mt < 4; ++mt)
#pragma unroll
      for (int nt = 0; nt < 8; ++nt)
        acc[mt][nt] = __builtin_amdgcn_mfma_f32_16x16x32_fp8_fp8(
            a0[mt], b0[nt], acc[mt][nt], 0, 0, 0);
    if (s + 2 < 32) {  // prefetch slab s+2
      const unsigned char* pA = A + (size_t)(s + 2) * 262144;
      const unsigned char* pB = B + (size_t)(s + 2) * 262144;
#pragma unroll
      for (int i = 0; i < 4; ++i) a0[i] = *(const long*)(pA + offA[i]);
#pragma unroll
      for (int j = 0; j < 8; ++j) b0[j] = *(const long*)(pB + offB[j]);
    }
#pragma unroll
    for (int mt = 0; mt < 4; ++mt)
#pragma unroll
      for (int nt = 0; nt < 8; ++nt)
        acc[mt][nt] = __builtin_amdgcn_mfma_f32_16x16x32_fp8_fp8(
            a1[mt], b1[nt], acc[mt][nt], 0, 0, 0);
  }

  // epilogue: exp (fixed-max LSE; |logit| <= 10, no overflow possible)
#pragma unroll
  for (int mt = 0; mt < 4; ++mt)
#pragma unroll
    for (int nt = 0; nt < 8; ++nt)
#pragma unroll
      for (int r = 0; r < 4; ++r)
        acc[mt][nt][r] = __expf(acc[mt][nt][r] * EPILOGUE_SCALE);

  // C/D layout: col = lane&15, row = (lane>>4)*4 + reg  [measured m89/m91]
#pragma unroll
  for (int mt = 0; mt < 4; ++mt)
#pragma unroll
    for (int r = 0; r < 4; ++r) {
      float v = 0.f;
#pragma unroll
      for (int nt = 0; nt < 8; ++nt) v += acc[mt][nt][r];
      v += __shfl_xor(v, 1, 64);
      v += __shfl_xor(v, 2, 64);
      v += __shfl_xor(v, 4, 64);
      v += __shfl_xor(v, 8, 64);
      if ((l & 15) == 0)
        atomicAdd(&rowsum[rowBase + w * 64 + mt * 16 + (l >> 4) * 4 + r], v);
    }
#pragma unroll
  for (int nt = 0; nt < 8; ++nt) {
    float v = 0.f;
#pragma unroll
    for (int mt = 0; mt < 4; ++mt)
      v += acc[mt][nt][0] + acc[mt][nt][1] + acc[mt][nt][2] + acc[mt][nt][3];
    v += __shfl_xor(v, 16, 64);
    v += __shfl_xor(v, 32, 64);
    if (l < 16)
      atomicAdd(&colsum[colBase + nt * 16 + l], v);
  }
}

// Kernel 3: scalar reduce.
__global__ __launch_bounds__(256) void finalize_k(
    const float* __restrict__ rowsum, const float* __restrict__ colsum,
    const float* __restrict__ diag, float* __restrict__ out) {
  const int t = threadIdx.x;
  float lse = 0.f, dg = 0.f;
  for (int i = t; i < N_; i += 256) {
    lse += __logf(rowsum[i]) + __logf(colsum[i]);
    dg += diag[i];
  }
#pragma unroll
  for (int o = 32; o > 0; o >>= 1) {
    lse += __shfl_down(lse, o, 64);
    dg  += __shfl_down(dg, o, 64);
  }
  __shared__ float red[2][4];
  const int w = t >> 6, l = t & 63;
  if (l == 0) { red[0][w] = lse; red[1][w] = dg; }
  __syncthreads();
  if (t == 0) {
    lse = red[0][0] + red[0][1] + red[0][2] + red[0][3];
    dg  = red[1][0] + red[1][1] + red[1][2] + red[1][3];
    out[0] = 0.5f * lse / (float)N_ - dg / (float)N_;
  }
}

extern "C" void kernel_launch(void* const* d_in, const int* in_sizes, int n_in,
                              void* d_out, int out_size, void* d_ws, size_t ws_size,
                              hipStream_t stream) {
  const float* im = (const float*)d_in[0];
  const float* cap = (const float*)d_in[1];
  float* out = (float*)d_out;
  char* ws = (char*)d_ws;
  unsigned char* imn = (unsigned char*)ws;                 // 8 MB fp8 (swizzled)
  unsigned char* capn = imn + (size_t)N_ * D_;             // 8 MB fp8 (swizzled)
  float* rowsum = (float*)(ws + 2 * (size_t)N_ * D_);
  float* colsum = rowsum + N_;
  float* diag = colsum + N_;

  normalize_k<<<512, 256, 0, stream>>>(im, cap, (unsigned int*)imn,
                                       (unsigned int*)capn, diag, rowsum);
  gemm_lse_k<<<dim3(32, 64), 256, 0, stream>>>(imn, capn, rowsum, colsum);
  finalize_k<<<1, 256, 0, stream>>>(rowsum, colsum, diag, out);
}

// Round 11
// 263.789 us; speedup vs baseline: 3.4687x; 1.0162x over previous
//
#include <hip/hip_runtime.h>
#include <stdint.h>

#define N_ 8192
#define D_ 1024
// logit = dot(imn,capn)/T; fp8 operands pre-scaled by 16 -> acc = 256*dot
#define EPILOGUE_SCALE (10.0f / 256.0f)
#define ENC_SCALE 16.0f

typedef float f32x4 __attribute__((ext_vector_type(4)));

// K=32 swizzled fragment layout (both operands), 8 MB each [R3/R5/R10-proven]:
//   dword index = s*65536 + tile*128 + fl*2 + h   (s in [0,32), tile in [0,512),
//   fl in [0,64), h in [0,2))
//   holds row = tile*16 + (fl&15), k-dwords [s*8 + (fl>>4)*2 + h]
// A wave's fragment load for (tile, s) is 64 lanes x 8B = 512B contiguous.

// Kernel 1: one 16-row tile per block. Phase 1: norms + diag. Phase 2: convert
// to fp8 via LDS. Phase 3: fully-coalesced uint4 stores in fragment order.
// Phase-3 chunks are built with MEMBER-WISE uint4 writes (compile-time q):
// R10's ((uint*)&va)[q] runtime-indexed form allocas -> scratch (~50 us lost).
// Blocks 0..15 also zero rowsum/colsum (replaces memset dispatch).
__global__ __launch_bounds__(256) void normalize_k(
    const float* __restrict__ im, const float* __restrict__ cap,
    unsigned int* __restrict__ imn, unsigned int* __restrict__ capn,
    float* __restrict__ diag, float* __restrict__ sums /* rowsum|colsum */) {
  __shared__ unsigned int ldsA[16 * 257];
  __shared__ unsigned int ldsB[16 * 257];
  const int til = blockIdx.x;
  const int t = threadIdx.x;
  if (til < 16) ((float4*)sums)[til * 256 + t] = (float4){0.f, 0.f, 0.f, 0.f};

  const int rloc = t >> 4, j = t & 15;
  const int row = til * 16 + rloc;
  const float4* __restrict__ aR = (const float4*)(im + (size_t)row * D_);
  const float4* __restrict__ bR = (const float4*)(cap + (size_t)row * D_);

  float ssa = 0.f, ssb = 0.f, dt = 0.f;
#pragma unroll
  for (int i = 0; i < 16; ++i) {
    const float4 a = aR[j + 16 * i];
    const float4 b = bR[j + 16 * i];
    ssa += a.x * a.x + a.y * a.y + a.z * a.z + a.w * a.w;
    ssb += b.x * b.x + b.y * b.y + b.z * b.z + b.w * b.w;
    dt  += a.x * b.x + a.y * b.y + a.z * b.z + a.w * b.w;
  }
#pragma unroll
  for (int o = 1; o < 16; o <<= 1) {  // reduce across the 16 lanes of this row
    ssa += __shfl_xor(ssa, o, 64);
    ssb += __shfl_xor(ssb, o, 64);
    dt  += __shfl_xor(dt, o, 64);
  }
  const float ra = rsqrtf(ssa), rb = rsqrtf(ssb);
  if (j == 0) diag[row] = dt * ra * rb * 10.0f;
  const float sa = ra * ENC_SCALE, sb = rb * ENC_SCALE;

  // phase 2: re-read (L1/L2 hot), convert, stage in LDS [row][k-dword]
#pragma unroll
  for (int i = 0; i < 16; ++i) {
    const float4 a = aR[j + 16 * i];
    const float4 b = bR[j + 16 * i];
    int pa = __builtin_amdgcn_cvt_pk_fp8_f32(a.x * sa, a.y * sa, 0, false);
    pa = __builtin_amdgcn_cvt_pk_fp8_f32(a.z * sa, a.w * sa, pa, true);
    int pb = __builtin_amdgcn_cvt_pk_fp8_f32(b.x * sb, b.y * sb, 0, false);
    pb = __builtin_amdgcn_cvt_pk_fp8_f32(b.z * sb, b.w * sb, pb, true);
    ldsA[rloc * 257 + j + 16 * i] = (unsigned int)pa;
    ldsB[rloc * 257 + j + 16 * i] = (unsigned int)pb;
  }
  __syncthreads();

  // phase 3: coalesced fragment-order stores, 4 uint4 chunks per thread.
  // chunk c4 covers dwords u = 4*c4..4*c4+3 -> fl = 2*c4 (+1), h = u&1.
#pragma unroll
  for (int i = 0; i < 4; ++i) {
    const int cid = i * 256 + t;       // 1024 chunks: slab s, 16B chunk c4
    const int s = cid >> 5, c4 = cid & 31;
    const int fl0 = c4 * 2, fl1 = fl0 + 1;
    const int i0 = (fl0 & 15) * 257 + s * 8 + (fl0 >> 4) * 2;
    const int i1 = (fl1 & 15) * 257 + s * 8 + (fl1 >> 4) * 2;
    uint4 va, vb;
    va.x = ldsA[i0]; va.y = ldsA[i0 + 1];
    va.z = ldsA[i1]; va.w = ldsA[i1 + 1];
    vb.x = ldsB[i0]; vb.y = ldsB[i0 + 1];
    vb.z = ldsB[i1]; vb.w = ldsB[i1 + 1];
    const size_t d = (size_t)s * 65536 + (size_t)til * 128 + c4 * 4;
    *(uint4*)(imn + d) = va;
    *(uint4*)(capn + d) = vb;
  }
}

// Kernel 2: no-LDS, no-barrier fp8 GEMM + exp + row/col partial sums.
// 256x128 block tile, 4 waves each a 64x128 slice (4x8 grid of 16x16x32
// MFMA tiles). Depth-2 prefetch with loads INTERLEAVED between MFMA rows
// (AITER-style) so the scheduler can emit fine-grained vmcnt waits without
// extra register liveness.
__global__ __launch_bounds__(256, 2) void gemm_lse_k(
    const unsigned char* __restrict__ A,   // swizzled imn
    const unsigned char* __restrict__ B,   // swizzled capn
    float* __restrict__ rowsum, float* __restrict__ colsum) {
  const int t = threadIdx.x;
  const int w = t >> 6, l = t & 63;
  const int rowBase = blockIdx.x * 256;
  const int colBase = blockIdx.y * 128;

  unsigned offA[4], offB[8];
#pragma unroll
  for (int i = 0; i < 4; ++i)
    offA[i] = (unsigned)((blockIdx.x * 16 + w * 4 + i) * 512 + l * 8);
#pragma unroll
  for (int j = 0; j < 8; ++j)
    offB[j] = (unsigned)((blockIdx.y * 8 + j) * 512 + l * 8);

  f32x4 acc[4][8];
#pragma unroll
  for (int i = 0; i < 4; ++i)
#pragma unroll
    for (int j = 0; j < 8; ++j)
      acc[i][j] = (f32x4){0.f, 0.f, 0.f, 0.f};

  long a0[4], b0[8], a1[4], b1[8];
#pragma unroll
  for (int i = 0; i < 4; ++i) a0[i] = *(const long*)(A + offA[i]);
#pragma unroll
  for (int j = 0; j < 8; ++j) b0[j] = *(const long*)(B + offB[j]);

#define MFMA_R(ar, br, mt)                                           \
  {                                                                  \
    _Pragma("unroll")                                                \
    for (int nt = 0; nt < 8; ++nt)                                   \
      acc[mt][nt] = __builtin_amdgcn_mfma_f32_16x16x32_fp8_fp8(      \
          ar[mt], br[nt], acc[mt][nt], 0, 0, 0);                     \
  }

#pragma unroll
  for (int s = 0; s < 32; s += 2) {
    {  // slab s+1 prefetch, interleaved between MFMA rows on slab s
      const unsigned char* pA = A + (size_t)(s + 1) * 262144;
      const unsigned char* pB = B + (size_t)(s + 1) * 262144;
      a1[0] = *(const long*)(pA + offA[0]);
      a1[1] = *(const long*)(pA + offA[1]);
      a1[2] = *(const long*)(pA + offA[2]);
      a1[3] = *(const long*)(pA + offA[3]);
      b1[0] = *(const long*)(pB + offB[0]);
      b1[1] = *(const long*)(pB + offB[1]);
      MFMA_R(a0, b0, 0)
      b1[2] = *(const long*)(pB + offB[2]);
      b1[3] = *(const long*)(pB + offB[3]);
      b1[4] = *(const long*)(pB + offB[4]);
      MFMA_R(a0, b0, 1)
      b1[5] = *(const long*)(pB + offB[5]);
      b1[6] = *(const long*)(pB + offB[6]);
      b1[7] = *(const long*)(pB + offB[7]);
      MFMA_R(a0, b0, 2)
      MFMA_R(a0, b0, 3)
    }
    if (s + 2 < 32) {  // slab s+2 prefetch, interleaved on slab s+1 compute
      const unsigned char* pA = A + (size_t)(s + 2) * 262144;
      const unsigned char* pB = B + (size_t)(s + 2) * 262144;
      a0[0] = *(const long*)(pA + offA[0]);
      a0[1] = *(const long*)(pA + offA[1]);
      a0[2] = *(const long*)(pA + offA[2]);
      a0[3] = *(const long*)(pA + offA[3]);
      b0[0] = *(const long*)(pB + offB[0]);
      b0[1] = *(const long*)(pB + offB[1]);
      MFMA_R(a1, b1, 0)
      b0[2] = *(const long*)(pB + offB[2]);
      b0[3] = *(const long*)(pB + offB[3]);
      b0[4] = *(const long*)(pB + offB[4]);
      MFMA_R(a1, b1, 1)
      b0[5] = *(const long*)(pB + offB[5]);
      b0[6] = *(const long*)(pB + offB[6]);
      b0[7] = *(const long*)(pB + offB[7]);
      MFMA_R(a1, b1, 2)
      MFMA_R(a1, b1, 3)
    } else {
      MFMA_R(a1, b1, 0)
      MFMA_R(a1, b1, 1)
      MFMA_R(a1, b1, 2)
      MFMA_R(a1, b1, 3)
    }
  }
#undef MFMA_R

  // epilogue: exp (fixed-max LSE; |logit| <= 10, no overflow possible)
#pragma unroll
  for (int mt = 0; mt < 4; ++mt)
#pragma unroll
    for (int nt = 0; nt < 8; ++nt)
#pragma unroll
      for (int r = 0; r < 4; ++r)
        acc[mt][nt][r] = __expf(acc[mt][nt][r] * EPILOGUE_SCALE);

  // C/D layout: col = lane&15, row = (lane>>4)*4 + reg  [measured m89/m91]
#pragma unroll
  for (int mt = 0; mt < 4; ++mt)
#pragma unroll
    for (int r = 0; r < 4; ++r) {
      float v = 0.f;
#pragma unroll
      for (int nt = 0; nt < 8; ++nt) v += acc[mt][nt][r];
      v += __shfl_xor(v, 1, 64);
      v += __shfl_xor(v, 2, 64);
      v += __shfl_xor(v, 4, 64);
      v += __shfl_xor(v, 8, 64);
      if ((l & 15) == 0)
        atomicAdd(&rowsum[rowBase + w * 64 + mt * 16 + (l >> 4) * 4 + r], v);
    }
#pragma unroll
  for (int nt = 0; nt < 8; ++nt) {
    float v = 0.f;
#pragma unroll
    for (int mt = 0; mt < 4; ++mt)
      v += acc[mt][nt][0] + acc[mt][nt][1] + acc[mt][nt][2] + acc[mt][nt][3];
    v += __shfl_xor(v, 16, 64);
    v += __shfl_xor(v, 32, 64);
    if (l < 16)
      atomicAdd(&colsum[colBase + nt * 16 + l], v);
  }
}

// Kernel 3: scalar reduce.
__global__ __launch_bounds__(256) void finalize_k(
    const float* __restrict__ rowsum, const float* __restrict__ colsum,
    const float* __restrict__ diag, float* __restrict__ out) {
  const int t = threadIdx.x;
  float lse = 0.f, dg = 0.f;
  for (int i = t; i < N_; i += 256) {
    lse += __logf(rowsum[i]) + __logf(colsum[i]);
    dg += diag[i];
  }
#pragma unroll
  for (int o = 32; o > 0; o >>= 1) {
    lse += __shfl_down(lse, o, 64);
    dg  += __shfl_down(dg, o, 64);
  }
  __shared__ float red[2][4];
  const int w = t >> 6, l = t & 63;
  if (l == 0) { red[0][w] = lse; red[1][w] = dg; }
  __syncthreads();
  if (t == 0) {
    lse = red[0][0] + red[0][1] + red[0][2] + red[0][3];
    dg  = red[1][0] + red[1][1] + red[1][2] + red[1][3];
    out[0] = 0.5f * lse / (float)N_ - dg / (float)N_;
  }
}

extern "C" void kernel_launch(void* const* d_in, const int* in_sizes, int n_in,
                              void* d_out, int out_size, void* d_ws, size_t ws_size,
                              hipStream_t stream) {
  const float* im = (const float*)d_in[0];
  const float* cap = (const float*)d_in[1];
  float* out = (float*)d_out;
  char* ws = (char*)d_ws;
  unsigned char* imn = (unsigned char*)ws;                 // 8 MB fp8 (swizzled)
  unsigned char* capn = imn + (size_t)N_ * D_;             // 8 MB fp8 (swizzled)
  float* rowsum = (float*)(ws + 2 * (size_t)N_ * D_);
  float* colsum = rowsum + N_;
  float* diag = colsum + N_;

  normalize_k<<<512, 256, 0, stream>>>(im, cap, (unsigned int*)imn,
                                       (unsigned int*)capn, diag, rowsum);
  gemm_lse_k<<<dim3(32, 64), 256, 0, stream>>>(imn, capn, rowsum, colsum);
  finalize_k<<<1, 256, 0, stream>>>(rowsum, colsum, diag, out);
}

// Round 12
// 255.774 us; speedup vs baseline: 3.5774x; 1.0313x over previous
//
#include <hip/hip_runtime.h>
#include <stdint.h>

#define N_ 8192
#define D_ 1024
// logit = dot(imn,capn)/T; fp8 operands pre-scaled by 16 -> acc = 256*dot
#define EPILOGUE_SCALE (10.0f / 256.0f)
#define ENC_SCALE 16.0f

typedef float f32x4 __attribute__((ext_vector_type(4)));

// K=32 swizzled fragment layout (both operands), 8 MB each [R3/R5/R10-proven]:
//   dword index = s*65536 + tile*128 + fl*2 + h   (s in [0,32), tile in [0,512),
//   fl in [0,64), h in [0,2))
//   holds row = tile*16 + (fl&15), k-dwords [s*8 + (fl>>4)*2 + h]
// A wave's fragment load for (tile, s) is 64 lanes x 8B = 512B contiguous.

// Kernel 1 (rewritten for occupancy): one 16-row tile per 1024-thread block,
// one WAVE per row (64 lanes = 1024 floats / 16 float4s... each lane holds 4
// float4 of im + 4 of cap in registers). Single pass: load once, wave-reduce
// norms via shuffle, convert from registers, LDS transpose, fragment-order
// stores. 512 blocks x 16 waves = full 32 waves/CU (old: 8 waves/CU,
// latency-pinned at ~90 us). Blocks 0..3 zero rowsum/colsum.
__global__ __launch_bounds__(1024) void normalize_k(
    const float* __restrict__ im, const float* __restrict__ cap,
    unsigned int* __restrict__ imn, unsigned int* __restrict__ capn,
    float* __restrict__ diag, float* __restrict__ sums /* rowsum|colsum */) {
  __shared__ unsigned int ldsA[16 * 257];
  __shared__ unsigned int ldsB[16 * 257];
  const int til = blockIdx.x;
  const int t = threadIdx.x;
  if (til < 4) ((float4*)sums)[til * 1024 + t] = (float4){0.f, 0.f, 0.f, 0.f};

  const int r = t >> 6, j = t & 63;   // wave r = row r of tile; lane j
  const int row = til * 16 + r;
  const float4* __restrict__ aR = (const float4*)(im + (size_t)row * D_);
  const float4* __restrict__ bR = (const float4*)(cap + (size_t)row * D_);

  float4 a0 = aR[j], a1 = aR[j + 64], a2 = aR[j + 128], a3 = aR[j + 192];
  float4 b0 = bR[j], b1 = bR[j + 64], b2 = bR[j + 128], b3 = bR[j + 192];

  float ssa = a0.x * a0.x + a0.y * a0.y + a0.z * a0.z + a0.w * a0.w
            + a1.x * a1.x + a1.y * a1.y + a1.z * a1.z + a1.w * a1.w
            + a2.x * a2.x + a2.y * a2.y + a2.z * a2.z + a2.w * a2.w
            + a3.x * a3.x + a3.y * a3.y + a3.z * a3.z + a3.w * a3.w;
  float ssb = b0.x * b0.x + b0.y * b0.y + b0.z * b0.z + b0.w * b0.w
            + b1.x * b1.x + b1.y * b1.y + b1.z * b1.z + b1.w * b1.w
            + b2.x * b2.x + b2.y * b2.y + b2.z * b2.z + b2.w * b2.w
            + b3.x * b3.x + b3.y * b3.y + b3.z * b3.z + b3.w * b3.w;
  float dt  = a0.x * b0.x + a0.y * b0.y + a0.z * b0.z + a0.w * b0.w
            + a1.x * b1.x + a1.y * b1.y + a1.z * b1.z + a1.w * b1.w
            + a2.x * b2.x + a2.y * b2.y + a2.z * b2.z + a2.w * b2.w
            + a3.x * b3.x + a3.y * b3.y + a3.z * b3.z + a3.w * b3.w;
#pragma unroll
  for (int o = 1; o < 64; o <<= 1) {  // full-wave butterfly (row = 1 wave)
    ssa += __shfl_xor(ssa, o, 64);
    ssb += __shfl_xor(ssb, o, 64);
    dt  += __shfl_xor(dt, o, 64);
  }
  const float ra = rsqrtf(ssa), rb = rsqrtf(ssb);
  if (j == 0) diag[row] = dt * ra * rb * 10.0f;
  const float sa = ra * ENC_SCALE, sb = rb * ENC_SCALE;

  // convert from registers; lane j owns k-dwords j, j+64, j+128, j+192
#define CVT_ST(av, bv, ofs)                                                  \
  {                                                                          \
    int pa_ = __builtin_amdgcn_cvt_pk_fp8_f32(av.x * sa, av.y * sa, 0, false); \
    pa_ = __builtin_amdgcn_cvt_pk_fp8_f32(av.z * sa, av.w * sa, pa_, true);  \
    int pb_ = __builtin_amdgcn_cvt_pk_fp8_f32(bv.x * sb, bv.y * sb, 0, false); \
    pb_ = __builtin_amdgcn_cvt_pk_fp8_f32(bv.z * sb, bv.w * sb, pb_, true);  \
    ldsA[r * 257 + j + (ofs)] = (unsigned int)pa_;                           \
    ldsB[r * 257 + j + (ofs)] = (unsigned int)pb_;                           \
  }
  CVT_ST(a0, b0, 0)
  CVT_ST(a1, b1, 64)
  CVT_ST(a2, b2, 128)
  CVT_ST(a3, b3, 192)
#undef CVT_ST
  __syncthreads();

  // phase 3: coalesced fragment-order stores, 1 uint4 chunk per thread.
  // chunk c4 covers dwords u = 4*c4..4*c4+3 -> fl = 2*c4 (+1), h = u&1.
  {
    const int s = t >> 5, c4 = t & 31;
    const int fl0 = c4 * 2, fl1 = fl0 + 1;
    const int i0 = (fl0 & 15) * 257 + s * 8 + (fl0 >> 4) * 2;
    const int i1 = (fl1 & 15) * 257 + s * 8 + (fl1 >> 4) * 2;
    uint4 va, vb;
    va.x = ldsA[i0]; va.y = ldsA[i0 + 1];
    va.z = ldsA[i1]; va.w = ldsA[i1 + 1];
    vb.x = ldsB[i0]; vb.y = ldsB[i0 + 1];
    vb.z = ldsB[i1]; vb.w = ldsB[i1 + 1];
    const size_t d = (size_t)s * 65536 + (size_t)til * 128 + c4 * 4;
    *(uint4*)(imn + d) = va;
    *(uint4*)(capn + d) = vb;
  }
}

// Kernel 2 [R11 verbatim — latency-pinned at ~163 us; interleave/pipeline
// variants all neutral, leave untouched]: no-LDS, no-barrier fp8 GEMM + exp
// + row/col partial sums. 256x128 block tile, 4 waves each a 64x128 slice.
__global__ __launch_bounds__(256, 2) void gemm_lse_k(
    const unsigned char* __restrict__ A,   // swizzled imn
    const unsigned char* __restrict__ B,   // swizzled capn
    float* __restrict__ rowsum, float* __restrict__ colsum) {
  const int t = threadIdx.x;
  const int w = t >> 6, l = t & 63;
  const int rowBase = blockIdx.x * 256;
  const int colBase = blockIdx.y * 128;

  unsigned offA[4], offB[8];
#pragma unroll
  for (int i = 0; i < 4; ++i)
    offA[i] = (unsigned)((blockIdx.x * 16 + w * 4 + i) * 512 + l * 8);
#pragma unroll
  for (int j = 0; j < 8; ++j)
    offB[j] = (unsigned)((blockIdx.y * 8 + j) * 512 + l * 8);

  f32x4 acc[4][8];
#pragma unroll
  for (int i = 0; i < 4; ++i)
#pragma unroll
    for (int j = 0; j < 8; ++j)
      acc[i][j] = (f32x4){0.f, 0.f, 0.f, 0.f};

  long a0[4], b0[8], a1[4], b1[8];
#pragma unroll
  for (int i = 0; i < 4; ++i) a0[i] = *(const long*)(A + offA[i]);
#pragma unroll
  for (int j = 0; j < 8; ++j) b0[j] = *(const long*)(B + offB[j]);

#define MFMA_R(ar, br, mt)                                           \
  {                                                                  \
    _Pragma("unroll")                                                \
    for (int nt = 0; nt < 8; ++nt)                                   \
      acc[mt][nt] = __builtin_amdgcn_mfma_f32_16x16x32_fp8_fp8(      \
          ar[mt], br[nt], acc[mt][nt], 0, 0, 0);                     \
  }

#pragma unroll
  for (int s = 0; s < 32; s += 2) {
    {  // slab s+1 prefetch, interleaved between MFMA rows on slab s
      const unsigned char* pA = A + (size_t)(s + 1) * 262144;
      const unsigned char* pB = B + (size_t)(s + 1) * 262144;
      a1[0] = *(const long*)(pA + offA[0]);
      a1[1] = *(const long*)(pA + offA[1]);
      a1[2] = *(const long*)(pA + offA[2]);
      a1[3] = *(const long*)(pA + offA[3]);
      b1[0] = *(const long*)(pB + offB[0]);
      b1[1] = *(const long*)(pB + offB[1]);
      MFMA_R(a0, b0, 0)
      b1[2] = *(const long*)(pB + offB[2]);
      b1[3] = *(const long*)(pB + offB[3]);
      b1[4] = *(const long*)(pB + offB[4]);
      MFMA_R(a0, b0, 1)
      b1[5] = *(const long*)(pB + offB[5]);
      b1[6] = *(const long*)(pB + offB[6]);
      b1[7] = *(const long*)(pB + offB[7]);
      MFMA_R(a0, b0, 2)
      MFMA_R(a0, b0, 3)
    }
    if (s + 2 < 32) {  // slab s+2 prefetch, interleaved on slab s+1 compute
      const unsigned char* pA = A + (size_t)(s + 2) * 262144;
      const unsigned char* pB = B + (size_t)(s + 2) * 262144;
      a0[0] = *(const long*)(pA + offA[0]);
      a0[1] = *(const long*)(pA + offA[1]);
      a0[2] = *(const long*)(pA + offA[2]);
      a0[3] = *(const long*)(pA + offA[3]);
      b0[0] = *(const long*)(pB + offB[0]);
      b0[1] = *(const long*)(pB + offB[1]);
      MFMA_R(a1, b1, 0)
      b0[2] = *(const long*)(pB + offB[2]);
      b0[3] = *(const long*)(pB + offB[3]);
      b0[4] = *(const long*)(pB + offB[4]);
      MFMA_R(a1, b1, 1)
      b0[5] = *(const long*)(pB + offB[5]);
      b0[6] = *(const long*)(pB + offB[6]);
      b0[7] = *(const long*)(pB + offB[7]);
      MFMA_R(a1, b1, 2)
      MFMA_R(a1, b1, 3)
    } else {
      MFMA_R(a1, b1, 0)
      MFMA_R(a1, b1, 1)
      MFMA_R(a1, b1, 2)
      MFMA_R(a1, b1, 3)
    }
  }
#undef MFMA_R

  // epilogue: exp (fixed-max LSE; |logit| <= 10, no overflow possible)
#pragma unroll
  for (int mt = 0; mt < 4; ++mt)
#pragma unroll
    for (int nt = 0; nt < 8; ++nt)
#pragma unroll
      for (int r = 0; r < 4; ++r)
        acc[mt][nt][r] = __expf(acc[mt][nt][r] * EPILOGUE_SCALE);

  // C/D layout: col = lane&15, row = (lane>>4)*4 + reg  [measured m89/m91]
#pragma unroll
  for (int mt = 0; mt < 4; ++mt)
#pragma unroll
    for (int r = 0; r < 4; ++r) {
      float v = 0.f;
#pragma unroll
      for (int nt = 0; nt < 8; ++nt) v += acc[mt][nt][r];
      v += __shfl_xor(v, 1, 64);
      v += __shfl_xor(v, 2, 64);
      v += __shfl_xor(v, 4, 64);
      v += __shfl_xor(v, 8, 64);
      if ((l & 15) == 0)
        atomicAdd(&rowsum[rowBase + w * 64 + mt * 16 + (l >> 4) * 4 + r], v);
    }
#pragma unroll
  for (int nt = 0; nt < 8; ++nt) {
    float v = 0.f;
#pragma unroll
    for (int mt = 0; mt < 4; ++mt)
      v += acc[mt][nt][0] + acc[mt][nt][1] + acc[mt][nt][2] + acc[mt][nt][3];
    v += __shfl_xor(v, 16, 64);
    v += __shfl_xor(v, 32, 64);
    if (l < 16)
      atomicAdd(&colsum[colBase + nt * 16 + l], v);
  }
}

// Kernel 3: scalar reduce.
__global__ __launch_bounds__(256) void finalize_k(
    const float* __restrict__ rowsum, const float* __restrict__ colsum,
    const float* __restrict__ diag, float* __restrict__ out) {
  const int t = threadIdx.x;
  float lse = 0.f, dg = 0.f;
  for (int i = t; i < N_; i += 256) {
    lse += __logf(rowsum[i]) + __logf(colsum[i]);
    dg += diag[i];
  }
#pragma unroll
  for (int o = 32; o > 0; o >>= 1) {
    lse += __shfl_down(lse, o, 64);
    dg  += __shfl_down(dg, o, 64);
  }
  __shared__ float red[2][4];
  const int w = t >> 6, l = t & 63;
  if (l == 0) { red[0][w] = lse; red[1][w] = dg; }
  __syncthreads();
  if (t == 0) {
    lse = red[0][0] + red[0][1] + red[0][2] + red[0][3];
    dg  = red[1][0] + red[1][1] + red[1][2] + red[1][3];
    out[0] = 0.5f * lse / (float)N_ - dg / (float)N_;
  }
}

extern "C" void kernel_launch(void* const* d_in, const int* in_sizes, int n_in,
                              void* d_out, int out_size, void* d_ws, size_t ws_size,
                              hipStream_t stream) {
  const float* im = (const float*)d_in[0];
  const float* cap = (const float*)d_in[1];
  float* out = (float*)d_out;
  char* ws = (char*)d_ws;
  unsigned char* imn = (unsigned char*)ws;                 // 8 MB fp8 (swizzled)
  unsigned char* capn = imn + (size_t)N_ * D_;             // 8 MB fp8 (swizzled)
  float* rowsum = (float*)(ws + 2 * (size_t)N_ * D_);
  float* colsum = rowsum + N_;
  float* diag = colsum + N_;

  normalize_k<<<512, 1024, 0, stream>>>(im, cap, (unsigned int*)imn,
                                        (unsigned int*)capn, diag, rowsum);
  gemm_lse_k<<<dim3(32, 64), 256, 0, stream>>>(imn, capn, rowsum, colsum);
  finalize_k<<<1, 256, 0, stream>>>(rowsum, colsum, diag, out);
}